// Round 4
// baseline (25088.304 us; speedup 1.0000x reference)
//
#include <hip/hip_runtime.h>

typedef unsigned int u32;
typedef unsigned short u16;

#define TPB 256

// ---------- bf16 helpers (LDS intermediates only; global I/O is fp32) ----------
__device__ __forceinline__ float bf2f(u16 v){ return __uint_as_float(((u32)v) << 16); }
__device__ __forceinline__ float bflo(u32 u){ return __uint_as_float(u << 16); }
__device__ __forceinline__ float bfhi(u32 u){ return __uint_as_float(u & 0xffff0000u); }
__device__ __forceinline__ u16 f2bf(float f){
  u32 u = __float_as_uint(f);
  u += 0x7fffu + ((u >> 16) & 1u);
  return (u16)(u >> 16);
}
__device__ __forceinline__ u32 pack2(float a, float b){
  return (u32)f2bf(a) | ((u32)f2bf(b) << 16);
}

// ---------- workspace layout (fp32 weights, zero-padded for float4 loads) ----------
// qW    [180][192] (180 valid)  off 0       size 34560
// kW    [180][192]              off 34560   size 34560
// vW    [180][192]              off 69120   size 34560
// projW [180][192]              off 103680  size 34560
// mlpW1 [180][768] (720 valid)  off 138240  size 138240
// mlpW2 [720][192] (180 valid)  off 276480  size 138240
#define OFF_QW   0
#define OFF_PROJ 103680
#define OFF_W1   138240
#define OFF_W2   276480
#define WS_FLOATS 414720

__global__ void swin_unpack_w(const float* __restrict__ qkvw, const float* __restrict__ projw,
                              const float* __restrict__ w1, const float* __restrict__ w2,
                              float* __restrict__ ws){
  int idx = blockIdx.x * TPB + threadIdx.x;
  if (idx >= WS_FLOATS) return;
  if (idx < 103680){                      // q/k/v blocks
    int ph = idx / 34560;                 // 0,1,2
    int t = idx - ph * 34560;
    int k = t / 192, c = t - k * 192;
    ws[idx] = (c < 180) ? qkvw[k * 540 + ph * 180 + c] : 0.f;
  } else if (idx < 138240){
    int t = idx - 103680; int k = t / 192, c = t - k * 192;
    ws[idx] = (c < 180) ? projw[k * 180 + c] : 0.f;
  } else if (idx < 276480){
    int t = idx - 138240; int k = t / 768, c = t - k * 768;
    ws[idx] = (c < 720) ? w1[k * 720 + c] : 0.f;
  } else {
    int t = idx - 276480; int k = t / 192, c = t - k * 192;
    ws[idx] = (c < 180) ? w2[k * 180 + c] : 0.f;
  }
}

// ---------- kernel 1: per-window LN1 + QKV + attention + proj + residual ----------
// grid = 4096 (B=4 * 32*32 windows), block = 256
__global__ __launch_bounds__(TPB, 1) void swin_attn(
    const float* __restrict__ x, const float* __restrict__ n1s, const float* __restrict__ n1b,
    const float* __restrict__ Wqkv, const float* __restrict__ qkvb,
    const float* __restrict__ Wp, const float* __restrict__ projb,
    float* out){
  __shared__ float xw[64][180];     // x fp32 -> LN'd h -> reused as attn output o
  __shared__ u16  qb[64][180];      // q (scaled), bf16
  __shared__ u16  kTb[180][64];     // k transposed, bf16
  __shared__ u16  vb[64][184];      // v, bf16 (pad cols 180..183 zeroed below)
  __shared__ u16  Sb[64][66];       // softmax probs, bf16 (row pad 66)
  __shared__ int  rowbase[64];      // global token row per window position

  const int tid = threadIdx.x;
  const int w = blockIdx.x;
  const int b = w >> 10, wy = (w >> 5) & 31, wx = w & 31;

  if (tid < 64){
    int iy = tid >> 3, ix = tid & 7;
    rowbase[tid] = b * 65536 + (wy * 8 + iy) * 256 + (wx * 8 + ix);
    *(u32*)&vb[tid][180] = 0;   // zero pad cols so PV's discarded lanes never read garbage
    *(u32*)&vb[tid][182] = 0;
  }
  __syncthreads();

  // ---- load x window (fp32, float4: 45 per row; row base 720B -> 16B aligned) ----
  for (int i = tid; i < 64 * 45; i += TPB){
    int n = i / 45, c4 = i - n * 45;
    const float4* px = (const float4*)(x + (size_t)rowbase[n] * 180);
    *(float4*)&xw[n][c4 * 4] = px[c4];
  }
  __syncthreads();

  // ---- LN1 (wave wv handles rows wv + 4r) ----
  {
    int lane = tid & 63, wv = tid >> 6;
    for (int r = 0; r < 16; ++r){
      int n = wv + 4 * r;
      float s = 0.f, ss = 0.f;
      for (int c = lane; c < 180; c += 64){ float v = xw[n][c]; s += v; ss += v * v; }
      for (int m = 32; m; m >>= 1){ s += __shfl_xor(s, m); ss += __shfl_xor(ss, m); }
      float mean = s * (1.f / 180.f);
      float var  = ss * (1.f / 180.f) - mean * mean;
      float rstd = rsqrtf(var + 1e-5f);
      for (int c = lane; c < 180; c += 64){
        float v = (xw[n][c] - mean) * rstd;
        xw[n][c] = v * n1s[c] + n1b[c];
      }
    }
  }
  __syncthreads();

  const int n = tid >> 2, j = tid & 3;

  // ---- QKV: 3 passes (q,k,v), thread (n,j) owns 48 cols (acc[48], no spill) ----
  for (int ph = 0; ph < 3; ++ph){
    const float* W = Wqkv + ph * 34560;
    float acc[48];
    #pragma unroll
    for (int i = 0; i < 48; ++i) acc[i] = 0.f;
    float4 buf[12];
    {
      const float4* w0 = (const float4*)(W + j * 48);
      #pragma unroll
      for (int i = 0; i < 12; ++i) buf[i] = w0[i];
    }
    for (int k = 0; k < 180; ++k){
      float4 nxt[12];
      const float4* wn = (const float4*)(W + ((k < 179) ? (k + 1) : k) * 192 + j * 48);
      #pragma unroll
      for (int i = 0; i < 12; ++i) nxt[i] = wn[i];
      float a = xw[n][k];
      #pragma unroll
      for (int i = 0; i < 12; ++i){
        acc[4*i+0] += a * buf[i].x; acc[4*i+1] += a * buf[i].y;
        acc[4*i+2] += a * buf[i].z; acc[4*i+3] += a * buf[i].w;
      }
      #pragma unroll
      for (int i = 0; i < 12; ++i) buf[i] = nxt[i];
    }
    #pragma unroll
    for (int i = 0; i < 48; ++i){
      int c = j * 48 + i;
      if (c < 180){
        float val = acc[i] + qkvb[ph * 180 + c];
        if (ph == 0)      qb[n][c] = f2bf(val * 0.18257418583505536f);  // q * HD^-0.5
        else if (ph == 1) kTb[c][n] = f2bf(val);
        else              vb[n][c] = f2bf(val);
      }
    }
  }
  __syncthreads();

  // ---- attention per head: S = q.k^T, softmax, o = P.v (rows quad-owned, same wave) ----
  for (int h = 0; h < 6; ++h){
    const int rq = tid >> 2, kg = tid & 3;
    float sv[16];
    #pragma unroll
    for (int i = 0; i < 16; ++i) sv[i] = 0.f;
    for (int d = 0; d < 30; ++d){
      float qv = bf2f(qb[rq][h * 30 + d]);
      const uint4* kr = (const uint4*)&kTb[h * 30 + d][kg * 16];
      uint4 ka = kr[0], kb2 = kr[1];
      sv[0]  += qv * bflo(ka.x);  sv[1]  += qv * bfhi(ka.x);
      sv[2]  += qv * bflo(ka.y);  sv[3]  += qv * bfhi(ka.y);
      sv[4]  += qv * bflo(ka.z);  sv[5]  += qv * bfhi(ka.z);
      sv[6]  += qv * bflo(ka.w);  sv[7]  += qv * bfhi(ka.w);
      sv[8]  += qv * bflo(kb2.x); sv[9]  += qv * bfhi(kb2.x);
      sv[10] += qv * bflo(kb2.y); sv[11] += qv * bfhi(kb2.y);
      sv[12] += qv * bflo(kb2.z); sv[13] += qv * bfhi(kb2.z);
      sv[14] += qv * bflo(kb2.w); sv[15] += qv * bfhi(kb2.w);
    }
    // softmax over the 64-key row (4 lanes per row; quad lives in one wave)
    float mx = sv[0];
    #pragma unroll
    for (int i = 1; i < 16; ++i) mx = fmaxf(mx, sv[i]);
    mx = fmaxf(mx, __shfl_xor(mx, 1)); mx = fmaxf(mx, __shfl_xor(mx, 2));
    float sum = 0.f;
    #pragma unroll
    for (int i = 0; i < 16; ++i){ sv[i] = __expf(sv[i] - mx); sum += sv[i]; }
    sum += __shfl_xor(sum, 1); sum += __shfl_xor(sum, 2);
    float inv = 1.f / sum;
    {
      u32* sp = (u32*)&Sb[rq][kg * 16];
      #pragma unroll
      for (int i = 0; i < 8; ++i) sp[i] = pack2(sv[2*i] * inv, sv[2*i+1] * inv);
    }
    // PV: thread (rq, g=kg) computes o[rq][h*30 + g*8 .. +7]
    float ov[8];
    #pragma unroll
    for (int i = 0; i < 8; ++i) ov[i] = 0.f;
    for (int mk = 0; mk < 64; ++mk){
      float p = bf2f(Sb[rq][mk]);
      const u32* vr = (const u32*)&vb[mk][h * 30];
      u32 u0 = vr[kg*4+0], u1 = vr[kg*4+1], u2 = vr[kg*4+2], u3 = vr[kg*4+3];
      ov[0] += p * bflo(u0); ov[1] += p * bfhi(u0);
      ov[2] += p * bflo(u1); ov[3] += p * bfhi(u1);
      ov[4] += p * bflo(u2); ov[5] += p * bfhi(u2);
      ov[6] += p * bflo(u3); ov[7] += p * bfhi(u3);
    }
    #pragma unroll
    for (int i = 0; i < 8; ++i){
      int d = kg * 8 + i;
      if (d < 30) xw[rq][h * 30 + d] = ov[i];
    }
  }
  __syncthreads();

  // ---- proj + bias + residual -> d_out (x2, fp32) ----
  {
    float acc[48];
    #pragma unroll
    for (int i = 0; i < 48; ++i) acc[i] = 0.f;
    float4 buf[12];
    {
      const float4* w0 = (const float4*)(Wp + j * 48);
      #pragma unroll
      for (int i = 0; i < 12; ++i) buf[i] = w0[i];
    }
    for (int k = 0; k < 180; ++k){
      float4 nxt[12];
      const float4* wn = (const float4*)(Wp + ((k < 179) ? (k + 1) : k) * 192 + j * 48);
      #pragma unroll
      for (int i = 0; i < 12; ++i) nxt[i] = wn[i];
      float a = xw[n][k];
      #pragma unroll
      for (int i = 0; i < 12; ++i){
        acc[4*i+0] += a * buf[i].x; acc[4*i+1] += a * buf[i].y;
        acc[4*i+2] += a * buf[i].z; acc[4*i+3] += a * buf[i].w;
      }
      #pragma unroll
      for (int i = 0; i < 12; ++i) buf[i] = nxt[i];
    }
    int g = rowbase[n];
    const float2* xr = (const float2*)(x + (size_t)g * 180);
    float2* outr = (float2*)(out + (size_t)g * 180);
    #pragma unroll
    for (int i2 = 0; i2 < 24; ++i2){
      int c = j * 48 + 2 * i2;
      if (c < 180){
        float2 xu = xr[c >> 1];
        float2 o2;
        o2.x = acc[2*i2]     + projb[c]     + xu.x;
        o2.y = acc[2*i2 + 1] + projb[c + 1] + xu.y;
        outr[c >> 1] = o2;
      }
    }
  }
}

// ---------- kernel 2: per-64-token LN2 + MLP(GELU) + residual, in-place on d_out (fp32) ----------
// grid = 4096 (262144 tokens / 64), block = 256
__global__ __launch_bounds__(TPB, 1) void swin_mlp(
    const float* __restrict__ n2s, const float* __restrict__ n2b,
    const float* __restrict__ W1, const float* __restrict__ b1,
    const float* __restrict__ W2, const float* __restrict__ b2,
    float* out){
  __shared__ u16 yb[64][180];   // x2 (bf16) -> LN'd activations (bf16)
  __shared__ u16 hb[64][720];   // hidden (post-GELU), bf16

  const int tid = threadIdx.x;
  const size_t base = (size_t)blockIdx.x * 64 * 180;

  // stage x2 rows (fp32 -> bf16)
  for (int i = tid; i < 64 * 90; i += TPB){
    float2 v = ((const float2*)(out + base))[i];
    ((u32*)&yb[0][0])[i] = pack2(v.x, v.y);
  }
  __syncthreads();

  // LN2 in place (stats on bf16-rounded x2: ~0.4% rel error, within budget)
  {
    int lane = tid & 63, wv = tid >> 6;
    for (int r = 0; r < 16; ++r){
      int n = wv + 4 * r;
      float s = 0.f, ss = 0.f;
      for (int c = lane; c < 180; c += 64){ float v = bf2f(yb[n][c]); s += v; ss += v * v; }
      for (int m = 32; m; m >>= 1){ s += __shfl_xor(s, m); ss += __shfl_xor(ss, m); }
      float mean = s * (1.f / 180.f);
      float var  = ss * (1.f / 180.f) - mean * mean;
      float rstd = rsqrtf(var + 1e-5f);
      for (int c = lane; c < 180; c += 64){
        float v = (bf2f(yb[n][c]) - mean) * rstd;
        yb[n][c] = f2bf(v * n2s[c] + n2b[c]);
      }
    }
  }
  __syncthreads();

  const int n = tid >> 2, j = tid & 3;

  // GEMM1 + GELU: hidden cols in 4 passes of 192 (48/thread)
  for (int p = 0; p < 4; ++p){
    float acc[48];
    #pragma unroll
    for (int i = 0; i < 48; ++i) acc[i] = 0.f;
    float4 buf[12];
    {
      const float4* w0 = (const float4*)(W1 + p * 192 + j * 48);
      #pragma unroll
      for (int i = 0; i < 12; ++i) buf[i] = w0[i];
    }
    for (int k = 0; k < 180; ++k){
      float4 nxt[12];
      const float4* wn = (const float4*)(W1 + ((k < 179) ? (k + 1) : k) * 768 + p * 192 + j * 48);
      #pragma unroll
      for (int i = 0; i < 12; ++i) nxt[i] = wn[i];
      float a = bf2f(yb[n][k]);
      #pragma unroll
      for (int i = 0; i < 12; ++i){
        acc[4*i+0] += a * buf[i].x; acc[4*i+1] += a * buf[i].y;
        acc[4*i+2] += a * buf[i].z; acc[4*i+3] += a * buf[i].w;
      }
      #pragma unroll
      for (int i = 0; i < 12; ++i) buf[i] = nxt[i];
    }
    #pragma unroll
    for (int i = 0; i < 48; ++i){
      int ch = p * 192 + j * 48 + i;
      if (ch < 720){
        float v = acc[i] + b1[ch];
        float gel = 0.5f * v * (1.f + erff(v * 0.70710678118654752f));  // exact GELU
        hb[n][ch] = f2bf(gel);
      }
    }
  }
  // hb rows are quad-owned within one wave: LDS ops are wave-ordered, no barrier needed

  // GEMM2 + bias + residual (in-place RMW of own elements, fp32)
  {
    float acc[48];
    #pragma unroll
    for (int i = 0; i < 48; ++i) acc[i] = 0.f;
    float4 buf[12];
    {
      const float4* w0 = (const float4*)(W2 + j * 48);
      #pragma unroll
      for (int i = 0; i < 12; ++i) buf[i] = w0[i];
    }
    for (int k = 0; k < 720; ++k){
      float4 nxt[12];
      const float4* wn = (const float4*)(W2 + ((k < 719) ? (k + 1) : k) * 192 + j * 48);
      #pragma unroll
      for (int i = 0; i < 12; ++i) nxt[i] = wn[i];
      float a = bf2f(hb[n][k]);
      #pragma unroll
      for (int i = 0; i < 12; ++i){
        acc[4*i+0] += a * buf[i].x; acc[4*i+1] += a * buf[i].y;
        acc[4*i+2] += a * buf[i].z; acc[4*i+3] += a * buf[i].w;
      }
      #pragma unroll
      for (int i = 0; i < 12; ++i) buf[i] = nxt[i];
    }
    float2* outr = (float2*)(out + base + (size_t)n * 180);
    #pragma unroll
    for (int i2 = 0; i2 < 24; ++i2){
      int c = j * 48 + 2 * i2;
      if (c < 180){
        float2 xu = outr[c >> 1];
        float2 o2;
        o2.x = acc[2*i2]     + b2[c]     + xu.x;
        o2.y = acc[2*i2 + 1] + b2[c + 1] + xu.y;
        outr[c >> 1] = o2;
      }
    }
  }
}

extern "C" void kernel_launch(void* const* d_in, const int* in_sizes, int n_in,
                              void* d_out, int out_size, void* d_ws, size_t ws_size,
                              hipStream_t stream){
  const float* x     = (const float*)d_in[0];
  const float* n1s   = (const float*)d_in[1];
  const float* n1b   = (const float*)d_in[2];
  const float* qkvw  = (const float*)d_in[3];
  const float* qkvb  = (const float*)d_in[4];
  const float* projw = (const float*)d_in[5];
  const float* projb = (const float*)d_in[6];
  const float* n2s   = (const float*)d_in[7];
  const float* n2b   = (const float*)d_in[8];
  const float* w1    = (const float*)d_in[9];
  const float* b1    = (const float*)d_in[10];
  const float* w2    = (const float*)d_in[11];
  const float* b2    = (const float*)d_in[12];
  float* outp = (float*)d_out;
  float* wsf = (float*)d_ws;

  swin_unpack_w<<<(WS_FLOATS + TPB - 1) / TPB, TPB, 0, stream>>>(qkvw, projw, w1, w2, wsf);
  swin_attn<<<4096, TPB, 0, stream>>>(x, n1s, n1b, wsf + OFF_QW, qkvb, wsf + OFF_PROJ, projb, outp);
  swin_mlp<<<4096, TPB, 0, stream>>>(n2s, n2b, wsf + OFF_W1, b1, wsf + OFF_W2, b2, outp);
}

// Round 5
// 1734.756 us; speedup vs baseline: 14.4622x; 14.4622x over previous
//
#include <hip/hip_runtime.h>

typedef unsigned int u32;
typedef unsigned short u16;
typedef __attribute__((ext_vector_type(8))) __bf16 bf16x8;
typedef __attribute__((ext_vector_type(4))) float f32x4;

#define TPB 256
#define MFMA(a,b,c) __builtin_amdgcn_mfma_f32_16x16x32_bf16(a,b,c,0,0,0)

__device__ __forceinline__ float bf2f(u16 v){ return __uint_as_float(((u32)v) << 16); }
__device__ __forceinline__ u16 f2bf(float f){
  u32 u = __float_as_uint(f);
  u += 0x7fffu + ((u >> 16) & 1u);
  return (u16)(u >> 16);
}

// ---------------- workspace (u16 units): fragment-major bf16 weights, hi+lo ----------------
// Wqkv: 36 nt x 6 kt x 64 lane x 8   (n: q=0..191,k=192..383,v=384..575; valid c<180, k<180)
// Wp:   12 nt x 6 kt x 512
// W1:   48 nt x 6 kt x 512           (n<720 valid, k<180 valid)
// W2:   12 nt x 23 kt x 512          (n<180 valid, k<720 valid)
#define OQKV_HI 0
#define OQKV_LO 110592
#define OWP_HI  221184
#define OWP_LO  258048
#define OW1_HI  294912
#define OW1_LO  442368
#define OW2_HI  589824
#define OW2_LO  731136
#define NW_TOT  436224

__global__ void swin_unpack(const float* __restrict__ qkvw, const float* __restrict__ projw,
                            const float* __restrict__ w1, const float* __restrict__ w2,
                            u16* __restrict__ ws){
  int idx = blockIdx.x * TPB + threadIdx.x;
  if (idx >= NW_TOT) return;
  float val = 0.f; int hi, lo;
  if (idx < 110592){
    int t = idx, nt = t / 3072, r = t % 3072, kt = r >> 9, e = r & 511;
    int lane = e >> 3, j = e & 7;
    int n = nt*16 + (lane & 15), k = kt*32 + (lane >> 4)*8 + j;
    int p = n / 192, c = n - p*192;
    if (c < 180 && k < 180) val = qkvw[k*540 + p*180 + c];
    hi = OQKV_HI + t; lo = OQKV_LO + t;
  } else if (idx < 147456){
    int t = idx - 110592, nt = t / 3072, r = t % 3072, kt = r >> 9, e = r & 511;
    int lane = e >> 3, j = e & 7;
    int n = nt*16 + (lane & 15), k = kt*32 + (lane >> 4)*8 + j;
    if (n < 180 && k < 180) val = projw[k*180 + n];
    hi = OWP_HI + t; lo = OWP_LO + t;
  } else if (idx < 294912){
    int t = idx - 147456, nt = t / 3072, r = t % 3072, kt = r >> 9, e = r & 511;
    int lane = e >> 3, j = e & 7;
    int n = nt*16 + (lane & 15), k = kt*32 + (lane >> 4)*8 + j;
    if (n < 720 && k < 180) val = w1[k*720 + n];
    hi = OW1_HI + t; lo = OW1_LO + t;
  } else {
    int t = idx - 294912, nt = t / 11776, r = t % 11776, kt = r >> 9, e = r & 511;
    int lane = e >> 3, j = e & 7;
    int n = nt*16 + (lane & 15), k = kt*32 + (lane >> 4)*8 + j;
    if (n < 180 && k < 720) val = w2[k*180 + n];
    hi = OW2_HI + t; lo = OW2_LO + t;
  }
  u16 h = f2bf(val);
  ws[hi] = h;
  ws[lo] = f2bf(val - bf2f(h));
}

// ---------------- kernel 1: per-window LN1 + QKV + attention + proj + residual ----------------
// LDS map (bytes): Y(y->o_hi) 0..25600 | Q 25600 | K 51200 | VT 76800 (192x144) |
//                  OLO 104448 | P 130048 (4x16x144) | rowbase 139264  => 139520 total
#define A_Y   0
#define A_Q   25600
#define A_K   51200
#define A_VT  76800
#define A_OLO 104448
#define A_P   130048
#define A_RB  139264

__global__ __launch_bounds__(TPB, 1) void swin_attn(
    const float* __restrict__ x, const float* __restrict__ n1s, const float* __restrict__ n1b,
    const u16* __restrict__ ws, const float* __restrict__ qkvb,
    const float* __restrict__ projb, float* __restrict__ out){
  __shared__ __align__(16) char sm[139520];
  const int tid = threadIdx.x;
  const int wv = tid >> 6, l = tid & 63, l15 = l & 15, lq = l >> 4;
  int* rb = (int*)(sm + A_RB);
  const f32x4 fz = {0.f, 0.f, 0.f, 0.f};

  if (tid < 64){
    int wb = blockIdx.x;
    int b = wb >> 10, wy = (wb >> 5) & 31, wx = wb & 31;
    rb[tid] = b * 65536 + (wy * 8 + (tid >> 3)) * 256 + (wx * 8 + (tid & 7));
  }
  // zero pads: q/k head-pad cols h*32+{30,31}; o_lo cols 180..191
  for (int i = tid; i < 2304; i += TPB){
    int a = i / 768, t = i - a*768, row = t / 12, pi = t - row*12;
    if (a < 2) *(u16*)(sm + (a ? A_K : A_Q) + row*400 + ((pi >> 1)*32 + 30 + (pi & 1))*2) = 0;
    else       *(u16*)(sm + A_OLO + row*400 + (180 + pi)*2) = 0;
  }
  __syncthreads();

  // LN1: wave wv owns rows [16wv, 16wv+16); fp32 stats; y bf16 (cols 180..191 = 0)
  for (int r = 0; r < 16; ++r){
    int n = wv*16 + r;
    size_t gb = (size_t)rb[n] * 180;
    float v0 = x[gb + l], v1 = x[gb + 64 + l];
    float v2 = (l < 52) ? x[gb + 128 + l] : 0.f;
    float s = v0 + v1 + v2, ss = v0*v0 + v1*v1 + v2*v2;
    #pragma unroll
    for (int m = 32; m; m >>= 1){ s += __shfl_xor(s, m); ss += __shfl_xor(ss, m); }
    float mean = s * (1.f/180.f);
    float rstd = rsqrtf(ss * (1.f/180.f) - mean*mean + 1e-5f);
    u16* yr = (u16*)(sm + A_Y + n*400);
    yr[l]      = f2bf((v0 - mean)*rstd*n1s[l] + n1b[l]);
    yr[64 + l] = f2bf((v1 - mean)*rstd*n1s[64+l] + n1b[64+l]);
    int c3 = 128 + l;
    yr[c3] = (c3 < 180) ? f2bf((v2 - mean)*rstd*n1s[c3] + n1b[c3]) : (u16)0;
  }
  __syncthreads();

  // QKV GEMM: y[64][192] x Wqkv[192][576] (hi+lo). Wave: 9 nt in 3 chunks of 3.
  {
    bf16x8 aA[6][4];
    #pragma unroll
    for (int kt = 0; kt < 6; ++kt)
      #pragma unroll
      for (int mt = 0; mt < 4; ++mt)
        aA[kt][mt] = *(const bf16x8*)(sm + A_Y + (mt*16 + l15)*400 + kt*64 + lq*16);
    for (int c3 = 0; c3 < 3; ++c3){
      int ntb = wv*9 + c3*3;
      f32x4 acc[4][3];
      #pragma unroll
      for (int mt = 0; mt < 4; ++mt)
        #pragma unroll
        for (int i = 0; i < 3; ++i) acc[mt][i] = fz;
      #pragma unroll
      for (int kt = 0; kt < 6; ++kt){
        bf16x8 bh[3], bl[3];
        #pragma unroll
        for (int i = 0; i < 3; ++i){
          bh[i] = *(const bf16x8*)(ws + OQKV_HI + ((ntb+i)*6 + kt)*512 + l*8);
          bl[i] = *(const bf16x8*)(ws + OQKV_LO + ((ntb+i)*6 + kt)*512 + l*8);
        }
        #pragma unroll
        for (int mt = 0; mt < 4; ++mt)
          #pragma unroll
          for (int i = 0; i < 3; ++i){
            acc[mt][i] = MFMA(aA[kt][mt], bh[i], acc[mt][i]);
            acc[mt][i] = MFMA(aA[kt][mt], bl[i], acc[mt][i]);
          }
      }
      #pragma unroll
      for (int i = 0; i < 3; ++i){
        int n = (ntb + i)*16 + l15;
        int p = n / 192, c = n - p*192;
        if (c < 180){
          float bias = qkvb[p*180 + c];
          int h = c / 30, d = c - h*30;
          int colp = h*32 + d;                     // head-padded layout
          #pragma unroll
          for (int mt = 0; mt < 4; ++mt)
            #pragma unroll
            for (int r = 0; r < 4; ++r){
              float val = acc[mt][i][r] + bias;
              int tok = mt*16 + lq*4 + r;
              if (p == 0)      *(u16*)(sm + A_Q + tok*400 + colp*2) = f2bf(val * 0.18257418583505536f);
              else if (p == 1) *(u16*)(sm + A_K + tok*400 + colp*2) = f2bf(val);
              else             *(u16*)(sm + A_VT + colp*144 + tok*2) = f2bf(val);
            }
        }
      }
    }
  }
  __syncthreads();

  // attention: wave wv owns S/O rows [16wv,16wv+16); P is wave-private LDS
  for (int h = 0; h < 6; ++h){
    bf16x8 aq = *(const bf16x8*)(sm + A_Q + (wv*16 + l15)*400 + h*64 + lq*16);
    f32x4 s[4];
    #pragma unroll
    for (int nt = 0; nt < 4; ++nt){
      bf16x8 bk = *(const bf16x8*)(sm + A_K + (nt*16 + l15)*400 + h*64 + lq*16);
      s[nt] = MFMA(aq, bk, fz);
    }
    #pragma unroll
    for (int r = 0; r < 4; ++r){
      float mx = fmaxf(fmaxf(s[0][r], s[1][r]), fmaxf(s[2][r], s[3][r]));
      mx = fmaxf(mx, __shfl_xor(mx, 1));
      mx = fmaxf(mx, __shfl_xor(mx, 2));
      mx = fmaxf(mx, __shfl_xor(mx, 4));
      mx = fmaxf(mx, __shfl_xor(mx, 8));
      float e0 = __expf(s[0][r] - mx), e1 = __expf(s[1][r] - mx);
      float e2 = __expf(s[2][r] - mx), e3 = __expf(s[3][r] - mx);
      float sum = e0 + e1 + e2 + e3;
      sum += __shfl_xor(sum, 1); sum += __shfl_xor(sum, 2);
      sum += __shfl_xor(sum, 4); sum += __shfl_xor(sum, 8);
      float iv = 1.f / sum;
      char* pr = sm + A_P + wv*2304 + (lq*4 + r)*144 + l15*2;
      *(u16*)(pr)      = f2bf(e0 * iv);
      *(u16*)(pr + 32) = f2bf(e1 * iv);
      *(u16*)(pr + 64) = f2bf(e2 * iv);
      *(u16*)(pr + 96) = f2bf(e3 * iv);
    }
    asm volatile("s_waitcnt lgkmcnt(0)" ::: "memory");
    f32x4 o0 = fz, o1 = fz;
    #pragma unroll
    for (int kt = 0; kt < 2; ++kt){
      bf16x8 aP  = *(const bf16x8*)(sm + A_P + wv*2304 + l15*144 + kt*64 + lq*16);
      bf16x8 bv0 = *(const bf16x8*)(sm + A_VT + (h*32 + l15)*144 + kt*64 + lq*16);
      bf16x8 bv1 = *(const bf16x8*)(sm + A_VT + (h*32 + 16 + l15)*144 + kt*64 + lq*16);
      o0 = MFMA(aP, bv0, o0);
      o1 = MFMA(aP, bv1, o1);
    }
    #pragma unroll
    for (int r = 0; r < 4; ++r){
      int tok = wv*16 + lq*4 + r;
      {
        int col = h*30 + l15;
        float v = o0[r]; u16 hh = f2bf(v);
        *(u16*)(sm + A_Y   + tok*400 + col*2) = hh;
        *(u16*)(sm + A_OLO + tok*400 + col*2) = f2bf(v - bf2f(hh));
      }
      if (l15 < 14){
        int col = h*30 + 16 + l15;
        float v = o1[r]; u16 hh = f2bf(v);
        *(u16*)(sm + A_Y   + tok*400 + col*2) = hh;
        *(u16*)(sm + A_OLO + tok*400 + col*2) = f2bf(v - bf2f(hh));
      }
    }
  }
  __syncthreads();

  // proj (o hi/lo x Wp hi/lo, 3-term) + bias + residual -> out fp32
  {
    f32x4 acc[4][3];
    #pragma unroll
    for (int mt = 0; mt < 4; ++mt)
      #pragma unroll
      for (int i = 0; i < 3; ++i) acc[mt][i] = fz;
    #pragma unroll
    for (int kt = 0; kt < 6; ++kt){
      bf16x8 ah[4], al[4], bh[3], bl[3];
      #pragma unroll
      for (int mt = 0; mt < 4; ++mt){
        ah[mt] = *(const bf16x8*)(sm + A_Y   + (mt*16 + l15)*400 + kt*64 + lq*16);
        al[mt] = *(const bf16x8*)(sm + A_OLO + (mt*16 + l15)*400 + kt*64 + lq*16);
      }
      #pragma unroll
      for (int i = 0; i < 3; ++i){
        bh[i] = *(const bf16x8*)(ws + OWP_HI + ((wv*3+i)*6 + kt)*512 + l*8);
        bl[i] = *(const bf16x8*)(ws + OWP_LO + ((wv*3+i)*6 + kt)*512 + l*8);
      }
      #pragma unroll
      for (int mt = 0; mt < 4; ++mt)
        #pragma unroll
        for (int i = 0; i < 3; ++i){
          acc[mt][i] = MFMA(ah[mt], bh[i], acc[mt][i]);
          acc[mt][i] = MFMA(al[mt], bh[i], acc[mt][i]);
          acc[mt][i] = MFMA(ah[mt], bl[i], acc[mt][i]);
        }
    }
    #pragma unroll
    for (int i = 0; i < 3; ++i){
      int col = (wv*3 + i)*16 + l15;
      if (col < 180){
        float bias = projb[col];
        #pragma unroll
        for (int mt = 0; mt < 4; ++mt)
          #pragma unroll
          for (int r = 0; r < 4; ++r){
            int tok = mt*16 + lq*4 + r;
            size_t off = (size_t)rb[tok]*180 + col;
            out[off] = acc[mt][i][r] + bias + x[off];
          }
      }
    }
  }
}

// ---------------- kernel 2: LN2 + MLP(GELU) + residual, in-place on d_out (fp32) ----------------
// LDS: Y 0..25600 (64x400B), G 25600..124928 (64x1552B)
#define M_Y 0
#define M_G 25600

__global__ __launch_bounds__(TPB, 1) void swin_mlp(
    const float* __restrict__ n2s, const float* __restrict__ n2b,
    const u16* __restrict__ ws, const float* __restrict__ b1, const float* __restrict__ b2,
    float* __restrict__ out){
  __shared__ __align__(16) char sm[124928];
  const int tid = threadIdx.x;
  const int wv = tid >> 6, l = tid & 63, l15 = l & 15, lq = l >> 4;
  const size_t base = (size_t)blockIdx.x * (64*180);
  const f32x4 fz = {0.f, 0.f, 0.f, 0.f};

  // LN2: fp32 stats from global x2
  for (int r = 0; r < 16; ++r){
    int n = wv*16 + r;
    const float* xr = out + base + n*180;
    float v0 = xr[l], v1 = xr[64 + l];
    float v2 = (l < 52) ? xr[128 + l] : 0.f;
    float s = v0 + v1 + v2, ss = v0*v0 + v1*v1 + v2*v2;
    #pragma unroll
    for (int m = 32; m; m >>= 1){ s += __shfl_xor(s, m); ss += __shfl_xor(ss, m); }
    float mean = s * (1.f/180.f);
    float rstd = rsqrtf(ss * (1.f/180.f) - mean*mean + 1e-5f);
    u16* yr = (u16*)(sm + M_Y + n*400);
    yr[l]      = f2bf((v0 - mean)*rstd*n2s[l] + n2b[l]);
    yr[64 + l] = f2bf((v1 - mean)*rstd*n2s[64+l] + n2b[64+l]);
    int c3 = 128 + l;
    yr[c3] = (c3 < 180) ? f2bf((v2 - mean)*rstd*n2s[c3] + n2b[c3]) : (u16)0;
  }
  __syncthreads();

  // GEMM1 + GELU: y[64][192] x W1[192][768] (hi+lo); wave: 12 nt in 3 chunks of 4
  {
    bf16x8 aA[6][4];
    #pragma unroll
    for (int kt = 0; kt < 6; ++kt)
      #pragma unroll
      for (int mt = 0; mt < 4; ++mt)
        aA[kt][mt] = *(const bf16x8*)(sm + M_Y + (mt*16 + l15)*400 + kt*64 + lq*16);
    for (int c4 = 0; c4 < 3; ++c4){
      int ntb = wv*12 + c4*4;
      f32x4 acc[4][4];
      #pragma unroll
      for (int mt = 0; mt < 4; ++mt)
        #pragma unroll
        for (int i = 0; i < 4; ++i) acc[mt][i] = fz;
      #pragma unroll
      for (int kt = 0; kt < 6; ++kt){
        bf16x8 bh[4], bl[4];
        #pragma unroll
        for (int i = 0; i < 4; ++i){
          bh[i] = *(const bf16x8*)(ws + OW1_HI + ((ntb+i)*6 + kt)*512 + l*8);
          bl[i] = *(const bf16x8*)(ws + OW1_LO + ((ntb+i)*6 + kt)*512 + l*8);
        }
        #pragma unroll
        for (int mt = 0; mt < 4; ++mt)
          #pragma unroll
          for (int i = 0; i < 4; ++i){
            acc[mt][i] = MFMA(aA[kt][mt], bh[i], acc[mt][i]);
            acc[mt][i] = MFMA(aA[kt][mt], bl[i], acc[mt][i]);
          }
      }
      #pragma unroll
      for (int i = 0; i < 4; ++i){
        int col = (ntb + i)*16 + l15;
        float bias = (col < 720) ? b1[col] : 0.f;
        #pragma unroll
        for (int mt = 0; mt < 4; ++mt)
          #pragma unroll
          for (int r = 0; r < 4; ++r){
            float v = acc[mt][i][r] + bias;
            float gel = (col < 720) ? 0.5f*v*(1.f + erff(v*0.70710678118654752f)) : 0.f;
            *(u16*)(sm + M_G + (mt*16 + lq*4 + r)*1552 + col*2) = f2bf(gel);
          }
      }
    }
  }
  __syncthreads();

  // GEMM2 + bias + residual: g[64][736] x W2[736][192] (hi+lo); wave: 3 nt
  {
    f32x4 acc[4][3];
    #pragma unroll
    for (int mt = 0; mt < 4; ++mt)
      #pragma unroll
      for (int i = 0; i < 3; ++i) acc[mt][i] = fz;
    for (int kt = 0; kt < 23; ++kt){
      bf16x8 a2[4], bh[3], bl[3];
      #pragma unroll
      for (int mt = 0; mt < 4; ++mt)
        a2[mt] = *(const bf16x8*)(sm + M_G + (mt*16 + l15)*1552 + kt*64 + lq*16);
      #pragma unroll
      for (int i = 0; i < 3; ++i){
        bh[i] = *(const bf16x8*)(ws + OW2_HI + ((wv*3+i)*23 + kt)*512 + l*8);
        bl[i] = *(const bf16x8*)(ws + OW2_LO + ((wv*3+i)*23 + kt)*512 + l*8);
      }
      #pragma unroll
      for (int mt = 0; mt < 4; ++mt)
        #pragma unroll
        for (int i = 0; i < 3; ++i){
          acc[mt][i] = MFMA(a2[mt], bh[i], acc[mt][i]);
          acc[mt][i] = MFMA(a2[mt], bl[i], acc[mt][i]);
        }
    }
    #pragma unroll
    for (int i = 0; i < 3; ++i){
      int col = (wv*3 + i)*16 + l15;
      if (col < 180){
        float bias = b2[col];
        #pragma unroll
        for (int mt = 0; mt < 4; ++mt)
          #pragma unroll
          for (int r = 0; r < 4; ++r){
            size_t off = base + (size_t)(mt*16 + lq*4 + r)*180 + col;
            out[off] += acc[mt][i][r] + bias;
          }
      }
    }
  }
}

extern "C" void kernel_launch(void* const* d_in, const int* in_sizes, int n_in,
                              void* d_out, int out_size, void* d_ws, size_t ws_size,
                              hipStream_t stream){
  const float* x     = (const float*)d_in[0];
  const float* n1s   = (const float*)d_in[1];
  const float* n1b   = (const float*)d_in[2];
  const float* qkvw  = (const float*)d_in[3];
  const float* qkvb  = (const float*)d_in[4];
  const float* projw = (const float*)d_in[5];
  const float* projb = (const float*)d_in[6];
  const float* n2s   = (const float*)d_in[7];
  const float* n2b   = (const float*)d_in[8];
  const float* w1    = (const float*)d_in[9];
  const float* b1    = (const float*)d_in[10];
  const float* w2    = (const float*)d_in[11];
  const float* b2    = (const float*)d_in[12];
  float* outp = (float*)d_out;
  u16* wsp = (u16*)d_ws;

  swin_unpack<<<(NW_TOT + TPB - 1) / TPB, TPB, 0, stream>>>(qkvw, projw, w1, w2, wsp);
  swin_attn<<<4096, TPB, 0, stream>>>(x, n1s, n1b, wsp, qkvb, projb, outp);
  swin_mlp<<<4096, TPB, 0, stream>>>(n2s, n2b, wsp, b1, b2, outp);
}